// Round 13
// baseline (91.541 us; speedup 1.0000x reference)
//
#include <hip/hip_runtime.h>

// EdgeEmbedding: B=8, L=256, A=15, K=9, EDGE_SIZE=16 — two kernels + 2MB d_ws.
//
// Output layout (all float32, concatenated flat):
//   [0,      30720)  block_id   = i/15
//   [30720,  32768)  batch_id   = i/256
//   [32768, 106496)  edges [2][36864]   (row0 src, row1 dst; intra then inter)
//   [106496,696320)  edge_attr [36864][16]
//
// Round-13 (R12 post-mortem: instruction-count cuts are the only lever that
// has ever moved this kernel; effective small-kernel clock ~2 GHz): move the
// trivial fills out of K2 into K1's dispatch as 960 dedicated fill blocks
// (K1's 1088 dist blocks leave ~half the CU capacity idle). K2 = selection
// only. Dist math and selection bit-identical to R12 (absmax 37).
//   K1 blocks [0,1088):  triangular 16x16 dist tiles, d^2 to both orders.
//   K1 blocks [1088,2048): flat-index fills of block_id/batch_id/edge_attr.
//   K2: per-row: read d^2 row, 128-bin histogram quantile -> T >= v9; mark
//       d <= T + DELTA (superset of f64 top-9); lazy f64 refine of near-ties
//       (EPS2) on ORIGINAL pos — bit-identical to the round-4 all-f64 kernel
//       that matched the oracle; rank -> ordered edge writes.

#define BB   8
#define LL   256
#define AA   15
#define KK   9

#define O_BATCH   30720
#define O_EDGES   32768
#define NE_HALF   18432   // B*L*K
#define NE        36864
#define O_ATTR    106496
#define N_FILL    622592  // 32768 + 589824 flat fill elements (attr mapped +O_ATTR-32768)
#define DELTA     0.005f
#define EPS2      2e-3
#define HBASE     448     // (0x38000000 >> 21)
#define NBIN      128
#define MAXM      128

#define TW        16      // tile width
#define NTILE     136     // 16*17/2 triangular tiles
#define NDIST     1088    // BB * NTILE

// ---------------------------------------------------------------------------
// K1: dist tiles (blocks < 1088) + output fills (blocks 1088..2047).
// ---------------------------------------------------------------------------
__global__ __launch_bounds__(256) void dist_fill_kernel(
    const float* __restrict__ pos,   // [B,L,A,3]
    const float* __restrict__ emb,   // [2,16]
    float*       __restrict__ D,     // [B,L,L]
    float*       __restrict__ out)
{
    const int bx  = blockIdx.x;
    const int tid = threadIdx.x;

    if (bx >= NDIST) {
        // ---- fill blocks: 960 x 768 flat slots over 622592 elements ----
        const int base = (bx - NDIST) * 768;
        #pragma unroll
        for (int k = 0; k < 3; ++k) {
            int gid = base + (k << 8) + tid;
            if (gid < 30720) {
                out[gid] = (float)(gid / AA);                    // block_id
            } else if (gid < 32768) {
                out[gid] = (float)((gid - 30720) >> 8);          // batch_id
            } else if (gid < N_FILL) {
                int a   = gid - 32768;                           // attr idx
                int sel = ((a >> 4) < NE_HALF) ? 0 : 16;
                out[O_ATTR + a] = emb[sel + (a & 15)];
            }
        }
        return;
    }

    // ---- dist tile ----
    const int b  = bx / NTILE;
    const int t  = bx - b * NTILE;
    // decode triangular index: off(r) = r*(33-r)/2
    int ti = (int)((33.0f - sqrtf(1089.0f - 8.0f * (float)t)) * 0.5f);
    while (ti * (33 - ti) / 2 > t) --ti;
    while ((ti + 1) * (32 - ti) / 2 <= t) ++ti;
    const int tj = ti + (t - ti * (33 - ti) / 2);
    const int I0 = ti * TW, J0 = tj * TW;

    __shared__ float4 sI[AA][TW];    // i-side: {-2x,-2y,-2z,x2}
    __shared__ float4 sJ[AA][TW];    // j-side: { x,  y,  z, x2}

    if (tid < 240) {                 // 240 atoms per side
        const int bl = tid / AA, a = tid - bl * AA;
        {
            const float* p = pos + ((size_t)(b * LL + I0 + bl) * 45) + a * 3;
            float x = p[0], y = p[1], z = p[2];
            sI[a][bl] = make_float4(-2.f*x, -2.f*y, -2.f*z, x*x + y*y + z*z);
        }
        {
            const float* p = pos + ((size_t)(b * LL + J0 + bl) * 45) + a * 3;
            float x = p[0], y = p[1], z = p[2];
            sJ[a][bl] = make_float4(x, y, z, x*x + y*y + z*z);
        }
    }
    __syncthreads();

    const int il = tid >> 4, jl = tid & 15;

    float4 J[AA];
    float  m[AA];
    #pragma unroll
    for (int c = 0; c < AA; ++c) { J[c] = sJ[c][jl]; m[c] = INFINITY; }

    #pragma unroll
    for (int a = 0; a < AA; ++a) {
        float4 A = sI[a][il];        // broadcast across 16 lanes
        #pragma unroll
        for (int c = 0; c < AA; ++c) {
            float dp = fmaf(A.x, J[c].x,
                       fmaf(A.y, J[c].y,
                       fmaf(A.z, J[c].z, A.w)));
            m[c] = fminf(m[c], dp);
        }
    }
    float v = INFINITY;
    #pragma unroll
    for (int c = 0; c < AA; ++c) v = fminf(v, m[c] + J[c].w);
    v = fmaxf(v, 0.0f);

    if (ti != tj || jl >= il) {
        const int i = I0 + il, j = J0 + jl;
        const size_t base = ((size_t)b) << 16;
        D[base + (i << 8) + j] = v;
        D[base + (j << 8) + i] = v;
    }
}

// ---------------------------------------------------------------------------
// K2: per-row selection.  grid = B * L.
// ---------------------------------------------------------------------------
__global__ __launch_bounds__(256) void select_kernel(
    const float* __restrict__ pos,   // [B,L,A,3] (f64 refine path)
    const float* __restrict__ D,     // [B,L,L] f32 min d^2
    const int*   __restrict__ frag,  // [B,L]
    float*       __restrict__ out)
{
    const int blk = blockIdx.x;      // = b*256 + i
    const int b   = blk >> 8;
    const int i   = blk & 255;
    const int j   = threadIdx.x;     // candidate dst block

    __shared__ double dAi[AA * 3];   // row-i coords (f64, refine path)
    __shared__ double dX2i[AA];
    __shared__ int    sHist[2 * NBIN];
    __shared__ int    sList[MAXM];   // (cand<<1)|class
    __shared__ double sVal[MAXM];    // key: promoted f32 or refined f64
    __shared__ int    sRList[MAXM];
    __shared__ int    sCnt, sRCnt;

    // ---- stage row-i atoms in f64 (refine path); zero hist ----
    if (j < AA) {
        const float* p = pos + (size_t)blk * 45 + j * 3;
        double dx = (double)p[0], dy = (double)p[1], dz = (double)p[2];
        dAi[3*j] = dx; dAi[3*j+1] = dy; dAi[3*j+2] = dz;
        dX2i[j] = dx*dx + dy*dy + dz*dz;
    }
    if (j < 2 * NBIN) sHist[j] = 0;
    if (j == 255) sCnt = 0;
    if (j == 254) sRCnt = 0;

    const int ftj  = frag[b * LL + j];
    const int segj = (ftj == 2) ? 1 : ftj;
    const int fti  = frag[blk];
    const int segi = (fti == 2) ? 1 : fti;
    // class: 0 = intra (seg==segi, j!=i), 1 = inter, -1 = self
    const int cls  = (j == i) ? -1 : ((segj == segi) ? 0 : 1);

    // ---- read d^2 from matrix (coalesced) ----
    const float d32 = D[(((size_t)b) << 16) + (i << 8) + j];
    __syncthreads();                                  // hist zero visible

    // ---- histogram (bits>>21 monotone for d32 >= 0) ----
    if (cls >= 0) {
        int bin = (int)(__float_as_uint(d32) >> 21) - HBASE;
        bin = min(NBIN - 1, max(0, bin));
        atomicAdd(&sHist[cls * NBIN + bin], 1);
    }
    __syncthreads();

    // ---- every wave scans both classes (2 bins/lane), T in registers ----
    const int lane = j & 63;
    float T[2];
    #pragma unroll
    for (int cw = 0; cw < 2; ++cw) {
        int c0 = sHist[cw * NBIN + 2*lane];
        int c1 = sHist[cw * NBIN + 2*lane + 1];
        int s  = c0 + c1;
        int cum = s;
        #pragma unroll
        for (int off = 1; off < 64; off <<= 1) {
            int v = __shfl_up(cum, off, 64);
            if (lane >= off) cum += v;
        }
        unsigned long long msk = __ballot(cum >= KK);
        float t_ = INFINITY;
        if (msk != 0ull) {
            int f = __builtin_ctzll(msk);
            if (lane == f) {
                int before = cum - s;
                int bin = (before + c0 >= KK) ? 2*f : 2*f + 1;
                t_ = (bin >= NBIN - 1) ? INFINITY
                   : __uint_as_float((unsigned)(HBASE + bin + 1) << 21);
            }
            t_ = __shfl(t_, f, 64);
        }
        T[cw] = t_;
    }

    // ---- mark superset; dense list + promoted-f32 keys ----
    if (cls >= 0 && d32 <= T[cls] + DELTA) {
        int p = atomicAdd(&sCnt, 1);
        if (p < MAXM) {
            sList[p] = (j << 1) | cls;
            sVal[p]  = (double)d32;
        }
    }
    __syncthreads();
    const int cnt = min(sCnt, MAXM);                  // ~20-28

    // ---- near-tie detection ----
    if (j < cnt) {
        double my = sVal[j];
        int mycls = sList[j] & 1;
        bool need = false;
        for (int u = 0; u < cnt; ++u) {
            if (u != j && (sList[u] & 1) == mycls &&
                fabs(sVal[u] - my) <= EPS2) need = true;
        }
        if (need) { int p = atomicAdd(&sRCnt, 1); sRList[p] = j; }
    }
    __syncthreads();

    // ---- rare cooperative f64 refine (usually rcnt == 0) ----
    {
        const int rcnt = sRCnt;
        const int wv = j >> 6;
        for (int base = 0; base < rcnt; base += 4) {
            int t = base + wv;
            double dmin = INFINITY;
            int slot = -1;
            if (t < rcnt) {
                slot = sRList[t];
                int cand = sList[slot] >> 1;
                const float* pc = pos + (size_t)(b * LL + cand) * 45;
                for (int p = lane; p < 225; p += 64) {
                    int a = p / 15, c = p - a * 15;
                    double cx = (double)pc[3*c], cy = (double)pc[3*c+1],
                           cz = (double)pc[3*c+2];
                    double dot = dAi[3*a]*cx + dAi[3*a+1]*cy + dAi[3*a+2]*cz;
                    double d2  = (dX2i[a] + (cx*cx + cy*cy + cz*cz))
                               - 2.0 * dot;
                    dmin = fmin(dmin, d2);
                }
            }
            #pragma unroll
            for (int off = 1; off < 64; off <<= 1)
                dmin = fmin(dmin, __shfl_xor(dmin, off, 64));
            if (lane == 0 && t < rcnt) sVal[slot] = fmax(dmin, 0.0);
        }
    }
    __syncthreads();

    // ---- rank per slot; winners write ordered edge slots ----
    if (j < cnt) {
        int e   = sList[j];
        int cnd = e >> 1, mycls = e & 1;
        double key = sVal[j];
        int r = 0;
        for (int u = 0; u < cnt; ++u) {
            int eu = sList[u];
            if ((eu & 1) == mycls) {
                double ku = sVal[u];
                int cu = eu >> 1;
                if (ku < key || (ku == key && cu < cnd)) ++r;
            }
        }
        if (r < KK) {
            int eo = (mycls == 0 ? 0 : NE_HALF) + blk * KK + r;
            out[O_EDGES + eo]      = (float)blk;            // src
            out[O_EDGES + NE + eo] = (float)(b * LL + cnd); // dst
        }
    }
}

extern "C" void kernel_launch(void* const* d_in, const int* in_sizes, int n_in,
                              void* d_out, int out_size, void* d_ws, size_t ws_size,
                              hipStream_t stream) {
    const float* pos  = (const float*)d_in[0];   // pos_heavyatom [8,256,15,3] f32
    const int*   frag = (const int*)d_in[6];     // fragment_type [8,256] i32
    const float* emb  = (const float*)d_in[7];   // edge_emb [2,16] f32
    float* out = (float*)d_out;
    float* Dm  = (float*)d_ws;                   // [8,256,256] f32 = 2 MB

    dist_fill_kernel<<<dim3(2048), dim3(256), 0, stream>>>(pos, emb, Dm, out);
    select_kernel<<<dim3(BB * LL), dim3(256), 0, stream>>>(pos, Dm, frag, out);
}